// Round 3
// baseline (1749.896 us; speedup 1.0000x reference)
//
#include <hip/hip_runtime.h>
#include <math.h>

#define NN 20000
#define NE 320000
#define DIM 256

typedef __bf16 bf16x8 __attribute__((ext_vector_type(8)));
typedef float f32x4 __attribute__((ext_vector_type(4)));
typedef int i32x4 __attribute__((ext_vector_type(4)));
typedef unsigned short u16x4 __attribute__((ext_vector_type(4)));

union B8 { i32x4 i; bf16x8 b; };

__device__ __forceinline__ unsigned short f2bf(float f) {
  unsigned int u; __builtin_memcpy(&u, &f, 4);
  u += 0x7fffu + ((u >> 16) & 1u);
  return (unsigned short)(u >> 16);
}
__device__ __forceinline__ float bf2f(unsigned short h) {
  unsigned int u = ((unsigned int)h) << 16;
  float f; __builtin_memcpy(&f, &u, 4);
  return f;
}

#define GLOAD16(gp, lp)                                                        \
  __builtin_amdgcn_global_load_lds(                                            \
      (const __attribute__((address_space(1))) unsigned int*)(gp),             \
      (__attribute__((address_space(3))) unsigned int*)(lp), 16, 0, 0)

// Pack one f32 [256][256] weight (row-major W[j_out][k]) into MFMA fragment order, bf16.
__global__ __launch_bounds__(256) void pack_w(const float* __restrict__ W,
                                              unsigned short* __restrict__ wf) {
  int t = blockIdx.x * 256 + threadIdx.x;    // 0..8191
  int lane = t & 63, ct = (t >> 6) & 15, ks = t >> 10;
  int col = ct * 16 + (lane & 15);
  int k0 = ks * 32 + (lane >> 4) * 8;
  const float* src = W + col * 256 + k0;
  unsigned int h[8];
#pragma unroll
  for (int j = 0; j < 8; j++) h[j] = f2bf(src[j]);
  i32x4 v;
  v.x = (int)(h[0] | (h[1] << 16));
  v.y = (int)(h[2] | (h[3] << 16));
  v.z = (int)(h[4] | (h[5] << 16));
  v.w = (int)(h[6] | (h[7] << 16));
  ((i32x4*)wf)[t] = v;
}

// Z = bf16(ea * x[dst]) -> zg rows at stride 512 u16 (first 256 used).
// Pure streaming gather kernel; high occupancy hides x-row latency.
__global__ __launch_bounds__(256) void zprep(const float* __restrict__ x,
                                             const int* __restrict__ ei,
                                             const float* __restrict__ ea,
                                             unsigned short* __restrict__ zg) {
  int idx = blockIdx.x * 256 + threadIdx.x;   // NE*16 threads
  int e = idx >> 4, c = idx & 15;             // 16-float chunk per thread
  int dst = ei[NE + e];
  const f32x4* ap = (const f32x4*)(ea + (size_t)e * DIM + c * 16);
  const f32x4* xp = (const f32x4*)(x + (size_t)dst * DIM + c * 16);
  unsigned int h[16];
#pragma unroll
  for (int j = 0; j < 4; j++) {
    f32x4 a = ap[j], b = xp[j];
    f32x4 p = a * b;
    h[j * 4 + 0] = f2bf(p.x); h[j * 4 + 1] = f2bf(p.y);
    h[j * 4 + 2] = f2bf(p.z); h[j * 4 + 3] = f2bf(p.w);
  }
  i32x4 o0, o1;
  o0.x = (int)(h[0] | (h[1] << 16));  o0.y = (int)(h[2] | (h[3] << 16));
  o0.z = (int)(h[4] | (h[5] << 16));  o0.w = (int)(h[6] | (h[7] << 16));
  o1.x = (int)(h[8] | (h[9] << 16));  o1.y = (int)(h[10] | (h[11] << 16));
  o1.z = (int)(h[12] | (h[13] << 16)); o1.w = (int)(h[14] | (h[15] << 16));
  i32x4* dp = (i32x4*)(zg + (size_t)e * 512 + c * 16);
  dp[0] = o0; dp[1] = o1;
}

// ---------- q kernel (64-row tiles) ----------
__device__ __forceinline__ void gemm_tile(const unsigned short* zs,
                                          const unsigned short* wf,
                                          int lane, int wv, f32x4 (&acc)[4][4]) {
#pragma unroll 1
  for (int ksI = 0; ksI < 8; ksI++) {
    bf16x8 afr[4], bfr[4];
#pragma unroll
    for (int rt = 0; rt < 4; rt++) {
      int row = rt * 16 + (lane & 15);
      int k = ksI * 32 + (lane >> 4) * 8;
      int byteo = (row * 512 + k * 2) ^ ((row & 7) << 4);
      B8 u; u.i = *(const i32x4*)((const char*)zs + byteo);
      afr[rt] = u.b;
    }
#pragma unroll
    for (int ct = 0; ct < 4; ct++) {
      B8 u; u.i = ((const i32x4*)wf)[ksI * 1024 + (wv * 4 + ct) * 64 + lane];
      bfr[ct] = u.b;
    }
#pragma unroll
    for (int rt = 0; rt < 4; rt++)
#pragma unroll
      for (int ct = 0; ct < 4; ct++)
        acc[rt][ct] = __builtin_amdgcn_mfma_f32_16x16x32_bf16(afr[rt], bfr[ct], acc[rt][ct], 0, 0, 0);
  }
}

__global__ __launch_bounds__(256) void q_kernel(const float* __restrict__ x,
                                                const unsigned short* __restrict__ wf,
                                                float* __restrict__ q) {
  __shared__ unsigned short zs[64 * 256];
  int tid = threadIdx.x, lane = tid & 63, wv = tid >> 6;
  int r0 = blockIdx.x * 64;
  int dcol = lane * 4;
#pragma unroll 4
  for (int rr = 0; rr < 16; rr++) {
    int r = rr * 4 + wv;
    int row = r0 + r;
    f32x4 a = {0.f, 0.f, 0.f, 0.f};
    if (row < NN) a = *(const f32x4*)(x + (size_t)row * DIM + dcol);
    u16x4 z;
    z.x = f2bf(a.x); z.y = f2bf(a.y); z.z = f2bf(a.z); z.w = f2bf(a.w);
    int byteo = (r * 512 + dcol * 2) ^ ((r & 7) << 4);
    *(u16x4*)((char*)zs + byteo) = z;
  }
  __syncthreads();
  f32x4 acc[4][4];
#pragma unroll
  for (int rt = 0; rt < 4; rt++)
#pragma unroll
    for (int ct = 0; ct < 4; ct++) acc[rt][ct] = (f32x4){0.f, 0.f, 0.f, 0.f};
  gemm_tile(zs, wf, lane, wv, acc);
  int cq = lane & 15, rq = lane >> 4;
#pragma unroll
  for (int ct = 0; ct < 4; ct++) {
    int col = wv * 64 + ct * 16 + cq;
#pragma unroll
    for (int rt = 0; rt < 4; rt++) {
#pragma unroll
      for (int j = 0; j < 4; j++) {
        int row = r0 + rt * 16 + rq * 4 + j;
        if (row < NN) q[(size_t)row * DIM + col] = acc[rt][ct][j];
      }
    }
  }
}

// ---------- edge GEMM: async-staged Z tile, 3 passes ----------
__global__ __launch_bounds__(512, 4) void gemm_edge(
    const unsigned short* __restrict__ zg, const int* __restrict__ ei,
    const int* __restrict__ pos,
    const unsigned short* __restrict__ wfk, const unsigned short* __restrict__ wfv,
    const unsigned short* __restrict__ wfe, const float* __restrict__ be,
    const float* __restrict__ q, unsigned short* __restrict__ vws,
    float* __restrict__ sperm, float* __restrict__ edge_out) {
  __shared__ unsigned short zs[128 * 256];   // 64 KiB, XOR-swizzled (chunk^(row&7))
  int tid = threadIdx.x, lane = tid & 63, wv = tid >> 6;
  int wm = wv >> 2, wn = wv & 3;
  int rq = lane >> 4, cl = lane & 15;
  int e0 = blockIdx.x * 128;

  const unsigned short* wfs[3] = {wfv, wfe, wfk};
  i32x4 wbuf[4][4];   // 4-slot ring, lead-2 weight prefetch (L2)
  i32x4 zbuf[2][4];   // 2-slot ring, lead-1 Z-fragment prefetch (LDS)
  f32x4 acc[4][4];

#define LOADW(S, SLOT)                                                         \
  {                                                                            \
    const unsigned short* wfp = wfs[(S) >> 3];                                 \
    _Pragma("unroll") for (int a = 0; a < 4; a++)                              \
        wbuf[SLOT][a] =                                                        \
            ((const i32x4*)wfp)[((S) & 7) * 1024 + (wn * 4 + a) * 64 + lane];  \
  }
#define LOADZ(S, SLOT)                                                         \
  {                                                                            \
    _Pragma("unroll") for (int b = 0; b < 4; b++) {                            \
      int row = wm * 64 + b * 16 + cl;                                         \
      int kk = ((S) & 7) * 32 + rq * 8;                                        \
      int byteo = (row * 512 + kk * 2) ^ ((row & 7) << 4);                     \
      zbuf[SLOT][b] = *(const i32x4*)((const char*)zs + byteo);                \
    }                                                                          \
  }
#define GEMM_PASS(P)                                                           \
  _Pragma("unroll") for (int a = 0; a < 4; a++)                                \
      _Pragma("unroll") for (int b = 0; b < 4; b++)                            \
          acc[a][b] = (f32x4){0.f, 0.f, 0.f, 0.f};                             \
  _Pragma("unroll") for (int ks = 0; ks < 8; ks++) {                           \
    const int step = (P) * 8 + ks;                                             \
    if (step + 2 < 24) LOADW(step + 2, (step + 2) & 3);                        \
    if (step + 1 < 24) LOADZ(step + 1, (step + 1) & 1);                        \
    _Pragma("unroll") for (int a = 0; a < 4; a++) {                            \
      B8 w; w.i = wbuf[step & 3][a];                                           \
      _Pragma("unroll") for (int b = 0; b < 4; b++) {                          \
        B8 z; z.i = zbuf[step & 1][b];                                         \
        acc[a][b] = __builtin_amdgcn_mfma_f32_16x16x32_bf16(w.b, z.b,          \
                                                            acc[a][b], 0, 0, 0); \
      }                                                                        \
    }                                                                          \
  }

  // async stage: 8 slabs x 16 rows; per wave 2 rows/slab; source pre-swizzled
  {
    int rl = wv * 2 + (lane >> 5);
    int c = lane & 31;
#pragma unroll
    for (int s = 0; s < 8; s++) {
      int r = s * 16 + rl;
      const unsigned short* gp = zg + (size_t)(e0 + r) * 512 + ((c ^ (r & 7)) * 8);
      unsigned short* lp = zs + (s * 16 + wv * 2) * 256;
      GLOAD16(gp, lp);
    }
  }
  LOADW(0, 0); LOADW(1, 1);   // L2 weight prefetch overlaps the DMA drain
  __syncthreads();
  LOADZ(0, 0); LOADZ(1, 1);

  // ---- pass 0: v = Z @ Wv^T -> bf16 ws ----
  GEMM_PASS(0)
#pragma unroll
  for (int a = 0; a < 4; a++) {
    int ch = wn * 64 + a * 16 + rq * 4;
#pragma unroll
    for (int b = 0; b < 4; b++) {
      int edge = wm * 64 + b * 16 + cl;
      u16x4 o;
      o.x = f2bf(acc[a][b][0]); o.y = f2bf(acc[a][b][1]);
      o.z = f2bf(acc[a][b][2]); o.w = f2bf(acc[a][b][3]);
      *(u16x4*)(vws + (size_t)(e0 + edge) * DIM + ch) = o;
    }
  }

  // ---- pass 1: edge_out = Z @ We^T + be (overwrites the Z halves) ----
  GEMM_PASS(1)
#pragma unroll
  for (int a = 0; a < 4; a++) {
    int ch = wn * 64 + a * 16 + rq * 4;
    f32x4 bias = *(const f32x4*)(be + ch);
#pragma unroll
    for (int b = 0; b < 4; b++) {
      int edge = wm * 64 + b * 16 + cl;
      f32x4 o = acc[a][b] + bias;
      *(f32x4*)(edge_out + (size_t)(e0 + edge) * DIM + ch) = o;
    }
  }

  // ---- pass 2: k = Z @ Wk^T, scores in-register, written CSR-permuted ----
  GEMM_PASS(2)
#pragma unroll
  for (int b = 0; b < 4; b++) {
    int edge = wm * 64 + b * 16 + cl;
    int sr = ei[e0 + edge];
    int pe = pos[e0 + edge];
    const float* qp = q + (size_t)sr * DIM + wn * 64 + rq * 4;
    f32x4 q0 = *(const f32x4*)(qp);
    f32x4 q1 = *(const f32x4*)(qp + 16);
    f32x4 q2 = *(const f32x4*)(qp + 32);
    f32x4 q3 = *(const f32x4*)(qp + 48);
    float s0 = acc[0][b][0] * q0[0] + acc[0][b][1] * q0[1] +
               acc[0][b][2] * q0[2] + acc[0][b][3] * q0[3] +
               acc[1][b][0] * q1[0] + acc[1][b][1] * q1[1] +
               acc[1][b][2] * q1[2] + acc[1][b][3] * q1[3];
    float s1 = acc[2][b][0] * q2[0] + acc[2][b][1] * q2[1] +
               acc[2][b][2] * q2[2] + acc[2][b][3] * q2[3] +
               acc[3][b][0] * q3[0] + acc[3][b][1] * q3[1] +
               acc[3][b][2] * q3[2] + acc[3][b][3] * q3[3];
    s0 += __shfl_xor(s0, 16); s0 += __shfl_xor(s0, 32);
    s1 += __shfl_xor(s1, 16); s1 += __shfl_xor(s1, 32);
    if (lane < 16) {
      sperm[(size_t)pe * 8 + wn * 2 + 0] = s0 * 0.17677669529663687f;
      sperm[(size_t)pe * 8 + wn * 2 + 1] = s1 * 0.17677669529663687f;
    }
  }
#undef LOADW
#undef LOADZ
#undef GEMM_PASS
}

// ---------- CSR build ----------
__global__ __launch_bounds__(256) void count_kernel(const int* __restrict__ ei,
                                                    int* __restrict__ counts) {
  int e = blockIdx.x * 256 + threadIdx.x;
  if (e < NE) atomicAdd(&counts[ei[e]], 1);
}

__global__ __launch_bounds__(256) void scan_kernel(const int* __restrict__ counts,
                                                   int* __restrict__ offs,
                                                   int* __restrict__ cursor) {
  __shared__ int tmp[256];
  __shared__ int carry;
  int tid = threadIdx.x;
  if (tid == 0) carry = 0;
  __syncthreads();
  for (int base = 0; base < NN; base += 256) {
    int i = base + tid;
    int v = (i < NN) ? counts[i] : 0;
    tmp[tid] = v;
    __syncthreads();
    for (int off = 1; off < 256; off <<= 1) {
      int t = (tid >= off) ? tmp[tid - off] : 0;
      __syncthreads();
      tmp[tid] += t;
      __syncthreads();
    }
    int incl = tmp[tid];
    int c0 = carry;
    if (i < NN) {
      offs[i] = c0 + incl - v;
      cursor[i] = c0 + incl - v;
    }
    __syncthreads();
    if (tid == 255) carry = c0 + incl;
    __syncthreads();
  }
  if (tid == 0) offs[NN] = carry;
}

__global__ __launch_bounds__(256) void fill_kernel(const int* __restrict__ ei,
                                                   int* __restrict__ cursor,
                                                   int* __restrict__ eids,
                                                   int* __restrict__ pos) {
  int e = blockIdx.x * 256 + threadIdx.x;
  if (e < NE) {
    int p = atomicAdd(&cursor[ei[e]], 1);
    eids[p] = e;
    pos[e] = p;
  }
}

// One wave per src node: online softmax; scores sequential (permuted), v gathered
// with a 2-stage pipeline.
__global__ __launch_bounds__(256) void node_kernel(const int* __restrict__ offs,
                                                   const int* __restrict__ eids,
                                                   const float* __restrict__ sperm,
                                                   const unsigned short* __restrict__ vws,
                                                   float* __restrict__ out) {
  int tid = threadIdx.x;
  int n = blockIdx.x * 4 + (tid >> 6);
  int lane = tid & 63, h = lane >> 3;
  int o0 = offs[n], deg = offs[n + 1] - o0;
  float m = -INFINITY, s = 0.f;
  float a0 = 0.f, a1 = 0.f, a2 = 0.f, a3 = 0.f;
  int e = (deg > 0) ? eids[o0] : 0;
  u16x4 v = *(const u16x4*)(vws + (size_t)e * DIM + lane * 4);
  for (int i = 0; i < deg; i++) {
    int en = (i + 1 < deg) ? eids[o0 + i + 1] : e;
    u16x4 vn = *(const u16x4*)(vws + (size_t)en * DIM + lane * 4);
    float sc = sperm[(size_t)(o0 + i) * 8 + h];
    float mn = fmaxf(m, sc);
    float scale = __expf(m - mn);
    float p = __expf(sc - mn);
    s = s * scale + p;
    m = mn;
    a0 = a0 * scale + p * bf2f(v.x);
    a1 = a1 * scale + p * bf2f(v.y);
    a2 = a2 * scale + p * bf2f(v.z);
    a3 = a3 * scale + p * bf2f(v.w);
    v = vn;
  }
  float inv = 1.f / (s + 1e-16f);
  f32x4 o;
  o.x = a0 * inv; o.y = a1 * inv; o.z = a2 * inv; o.w = a3 * inv;
  *(f32x4*)(out + (size_t)n * DIM + lane * 4) = o;
}

extern "C" void kernel_launch(void* const* d_in, const int* in_sizes, int n_in,
                              void* d_out, int out_size, void* d_ws, size_t ws_size,
                              hipStream_t stream) {
  const float* x = (const float*)d_in[0];
  const int* ei = (const int*)d_in[1];
  const float* ea = (const float*)d_in[2];
  const float* Wq = (const float*)d_in[3];
  const float* Wk = (const float*)d_in[4];
  const float* Wv = (const float*)d_in[5];
  const float* We = (const float*)d_in[6];
  const float* be = (const float*)d_in[7];

  float* out = (float*)d_out;                       // [NN, 256]
  float* edge_out = out + (size_t)NN * DIM;         // [NE, 256] f32
  unsigned short* zg = (unsigned short*)edge_out;   // Z bf16 in rows' first half (stride 512 u16)
  float* q = out;                                   // q scratch (overwritten by node_kernel)

  char* ws = (char*)d_ws;
  unsigned short* wfq = (unsigned short*)(ws + 0);
  unsigned short* wfk = (unsigned short*)(ws + 131072);
  unsigned short* wfv = (unsigned short*)(ws + 262144);
  unsigned short* wfe = (unsigned short*)(ws + 393216);
  unsigned short* vws = (unsigned short*)(ws + 524288);            // [NE,256] bf16
  float* sperm = (float*)(ws + 524288 + 163840000);                // [NE,8] f32, CSR order
  int* counts = (int*)(ws + 524288 + 163840000 + 10240000);
  int* offs   = (int*)(ws + 524288 + 163840000 + 10240000 + 80000);
  int* cursor = (int*)(ws + 524288 + 163840000 + 10240000 + 160016);
  int* eids   = (int*)(ws + 524288 + 163840000 + 10240000 + 240016);
  int* pos    = (int*)(ws + 524288 + 163840000 + 10240000 + 240016 + 1280000);

  hipMemsetAsync(counts, 0, NN * sizeof(int), stream);

  pack_w<<<32, 256, 0, stream>>>(Wq, wfq);
  pack_w<<<32, 256, 0, stream>>>(Wk, wfk);
  pack_w<<<32, 256, 0, stream>>>(Wv, wfv);
  pack_w<<<32, 256, 0, stream>>>(We, wfe);

  zprep<<<NE / 16, 256, 0, stream>>>(x, ei, ea, zg);

  count_kernel<<<(NE + 255) / 256, 256, 0, stream>>>(ei, counts);
  scan_kernel<<<1, 256, 0, stream>>>(counts, offs, cursor);
  fill_kernel<<<(NE + 255) / 256, 256, 0, stream>>>(ei, cursor, eids, pos);

  q_kernel<<<(NN + 63) / 64, 256, 0, stream>>>(x, wfq, q);

  gemm_edge<<<NE / 128, 512, 0, stream>>>(zg, ei, pos, wfk, wfv, wfe, be, q,
                                          vws, sperm, edge_out);

  node_kernel<<<NN / 4, 256, 0, stream>>>(offs, eids, sperm, vws, out);
}

// Round 4
// 619.798 us; speedup vs baseline: 2.8233x; 2.8233x over previous
//
#include <hip/hip_runtime.h>
#include <math.h>

#define NN 20000
#define NE 320000
#define DIM 256

typedef __bf16 bf16x8 __attribute__((ext_vector_type(8)));
typedef float f32x4 __attribute__((ext_vector_type(4)));
typedef int i32x4 __attribute__((ext_vector_type(4)));
typedef unsigned short u16x4 __attribute__((ext_vector_type(4)));

union B8 { i32x4 i; bf16x8 b; };

__device__ __forceinline__ unsigned short f2bf(float f) {
  unsigned int u; __builtin_memcpy(&u, &f, 4);
  u += 0x7fffu + ((u >> 16) & 1u);
  return (unsigned short)(u >> 16);
}
__device__ __forceinline__ float bf2f(unsigned short h) {
  unsigned int u = ((unsigned int)h) << 16;
  float f; __builtin_memcpy(&f, &u, 4);
  return f;
}

#define GLOAD16(gp, lp)                                                        \
  __builtin_amdgcn_global_load_lds(                                            \
      (const __attribute__((address_space(1))) unsigned int*)(gp),             \
      (__attribute__((address_space(3))) unsigned int*)(lp), 16, 0, 0)

// Pack one f32 [256][256] weight (row-major W[j_out][k]) into MFMA fragment order, bf16.
__global__ __launch_bounds__(256) void pack_w(const float* __restrict__ W,
                                              unsigned short* __restrict__ wf) {
  int t = blockIdx.x * 256 + threadIdx.x;    // 0..8191
  int lane = t & 63, ct = (t >> 6) & 15, ks = t >> 10;
  int col = ct * 16 + (lane & 15);
  int k0 = ks * 32 + (lane >> 4) * 8;
  const float* src = W + col * 256 + k0;
  unsigned int h[8];
#pragma unroll
  for (int j = 0; j < 8; j++) h[j] = f2bf(src[j]);
  i32x4 v;
  v.x = (int)(h[0] | (h[1] << 16));
  v.y = (int)(h[2] | (h[3] << 16));
  v.z = (int)(h[4] | (h[5] << 16));
  v.w = (int)(h[6] | (h[7] << 16));
  ((i32x4*)wf)[t] = v;
}

// Z = bf16(ea * x[dst]) -> zg rows at stride 512 u16 (first 256 used).
__global__ __launch_bounds__(256) void zprep(const float* __restrict__ x,
                                             const int* __restrict__ ei,
                                             const float* __restrict__ ea,
                                             unsigned short* __restrict__ zg) {
  int idx = blockIdx.x * 256 + threadIdx.x;   // NE*16 threads
  int e = idx >> 4, c = idx & 15;             // 16-float chunk per thread
  int dst = ei[NE + e];
  const f32x4* ap = (const f32x4*)(ea + (size_t)e * DIM + c * 16);
  const f32x4* xp = (const f32x4*)(x + (size_t)dst * DIM + c * 16);
  unsigned int h[16];
#pragma unroll
  for (int j = 0; j < 4; j++) {
    f32x4 a = ap[j], b = xp[j];
    f32x4 p = a * b;
    h[j * 4 + 0] = f2bf(p.x); h[j * 4 + 1] = f2bf(p.y);
    h[j * 4 + 2] = f2bf(p.z); h[j * 4 + 3] = f2bf(p.w);
  }
  i32x4 o0, o1;
  o0.x = (int)(h[0] | (h[1] << 16));  o0.y = (int)(h[2] | (h[3] << 16));
  o0.z = (int)(h[4] | (h[5] << 16));  o0.w = (int)(h[6] | (h[7] << 16));
  o1.x = (int)(h[8] | (h[9] << 16));  o1.y = (int)(h[10] | (h[11] << 16));
  o1.z = (int)(h[12] | (h[13] << 16)); o1.w = (int)(h[14] | (h[15] << 16));
  i32x4* dp = (i32x4*)(zg + (size_t)e * 512 + c * 16);
  dp[0] = o0; dp[1] = o1;
}

// ---------- q kernel (64-row tiles) ----------
__device__ __forceinline__ void gemm_tile(const unsigned short* zs,
                                          const unsigned short* wf,
                                          int lane, int wv, f32x4 (&acc)[4][4]) {
#pragma unroll 1
  for (int ksI = 0; ksI < 8; ksI++) {
    bf16x8 afr[4], bfr[4];
#pragma unroll
    for (int rt = 0; rt < 4; rt++) {
      int row = rt * 16 + (lane & 15);
      int k = ksI * 32 + (lane >> 4) * 8;
      int byteo = (row * 512 + k * 2) ^ ((row & 7) << 4);
      B8 u; u.i = *(const i32x4*)((const char*)zs + byteo);
      afr[rt] = u.b;
    }
#pragma unroll
    for (int ct = 0; ct < 4; ct++) {
      B8 u; u.i = ((const i32x4*)wf)[ksI * 1024 + (wv * 4 + ct) * 64 + lane];
      bfr[ct] = u.b;
    }
#pragma unroll
    for (int rt = 0; rt < 4; rt++)
#pragma unroll
      for (int ct = 0; ct < 4; ct++)
        acc[rt][ct] = __builtin_amdgcn_mfma_f32_16x16x32_bf16(afr[rt], bfr[ct], acc[rt][ct], 0, 0, 0);
  }
}

__global__ __launch_bounds__(256) void q_kernel(const float* __restrict__ x,
                                                const unsigned short* __restrict__ wf,
                                                float* __restrict__ q) {
  __shared__ unsigned short zs[64 * 256];
  int tid = threadIdx.x, lane = tid & 63, wv = tid >> 6;
  int r0 = blockIdx.x * 64;
  int dcol = lane * 4;
#pragma unroll 4
  for (int rr = 0; rr < 16; rr++) {
    int r = rr * 4 + wv;
    int row = r0 + r;
    f32x4 a = {0.f, 0.f, 0.f, 0.f};
    if (row < NN) a = *(const f32x4*)(x + (size_t)row * DIM + dcol);
    u16x4 z;
    z.x = f2bf(a.x); z.y = f2bf(a.y); z.z = f2bf(a.z); z.w = f2bf(a.w);
    int byteo = (r * 512 + dcol * 2) ^ ((r & 7) << 4);
    *(u16x4*)((char*)zs + byteo) = z;
  }
  __syncthreads();
  f32x4 acc[4][4];
#pragma unroll
  for (int rt = 0; rt < 4; rt++)
#pragma unroll
    for (int ct = 0; ct < 4; ct++) acc[rt][ct] = (f32x4){0.f, 0.f, 0.f, 0.f};
  gemm_tile(zs, wf, lane, wv, acc);
  int cq = lane & 15, rq = lane >> 4;
#pragma unroll
  for (int ct = 0; ct < 4; ct++) {
    int col = wv * 64 + ct * 16 + cq;
#pragma unroll
    for (int rt = 0; rt < 4; rt++) {
#pragma unroll
      for (int j = 0; j < 4; j++) {
        int row = r0 + rt * 16 + rq * 4 + j;
        if (row < NN) q[(size_t)row * DIM + col] = acc[rt][ct][j];
      }
    }
  }
}

// ---------- edge GEMM: async-staged Z tile, 3 passes ----------
__global__ __launch_bounds__(512) void gemm_edge(
    const unsigned short* __restrict__ zg, const int* __restrict__ ei,
    const int* __restrict__ pos,
    const unsigned short* __restrict__ wfk, const unsigned short* __restrict__ wfv,
    const unsigned short* __restrict__ wfe, const float* __restrict__ be,
    const float* __restrict__ q, unsigned short* __restrict__ vws,
    float* __restrict__ sperm, float* __restrict__ edge_out) {
  __shared__ unsigned short zs[128 * 256];   // 64 KiB, XOR-swizzled (chunk^(row&7))
  int tid = threadIdx.x, lane = tid & 63, wv = tid >> 6;
  int wm = wv >> 2, wn = wv & 3;
  int rq = lane >> 4, cl = lane & 15;
  int e0 = blockIdx.x * 128;

  const unsigned short* wfs[3] = {wfv, wfe, wfk};
  i32x4 wbuf[4][4];   // 4-slot ring, lead-2 weight prefetch (L2)
  i32x4 zbuf[2][4];   // 2-slot ring, lead-1 Z-fragment prefetch (LDS)
  f32x4 acc[4][4];

#define LOADW(S, SLOT)                                                         \
  {                                                                            \
    const unsigned short* wfp = wfs[(S) >> 3];                                 \
    _Pragma("unroll") for (int a = 0; a < 4; a++)                              \
        wbuf[SLOT][a] =                                                        \
            ((const i32x4*)wfp)[((S) & 7) * 1024 + (wn * 4 + a) * 64 + lane];  \
  }
#define LOADZ(S, SLOT)                                                         \
  {                                                                            \
    _Pragma("unroll") for (int b = 0; b < 4; b++) {                            \
      int row = wm * 64 + b * 16 + cl;                                         \
      int kk = ((S) & 7) * 32 + rq * 8;                                        \
      int byteo = (row * 512 + kk * 2) ^ ((row & 7) << 4);                     \
      zbuf[SLOT][b] = *(const i32x4*)((const char*)zs + byteo);                \
    }                                                                          \
  }
#define GEMM_PASS(P)                                                           \
  _Pragma("unroll") for (int a = 0; a < 4; a++)                                \
      _Pragma("unroll") for (int b = 0; b < 4; b++)                            \
          acc[a][b] = (f32x4){0.f, 0.f, 0.f, 0.f};                             \
  _Pragma("unroll") for (int ks = 0; ks < 8; ks++) {                           \
    const int step = (P) * 8 + ks;                                             \
    if (step + 2 < 24) LOADW(step + 2, (step + 2) & 3);                        \
    if (step + 1 < 24) LOADZ(step + 1, (step + 1) & 1);                        \
    _Pragma("unroll") for (int a = 0; a < 4; a++) {                            \
      B8 w; w.i = wbuf[step & 3][a];                                           \
      _Pragma("unroll") for (int b = 0; b < 4; b++) {                          \
        B8 z; z.i = zbuf[step & 1][b];                                         \
        acc[a][b] = __builtin_amdgcn_mfma_f32_16x16x32_bf16(w.b, z.b,          \
                                                            acc[a][b], 0, 0, 0); \
      }                                                                        \
    }                                                                          \
  }

  // async stage: 8 slabs x 16 rows; per wave 2 rows/slab; source pre-swizzled
  {
    int rl = wv * 2 + (lane >> 5);
    int c = lane & 31;
#pragma unroll
    for (int s = 0; s < 8; s++) {
      int r = s * 16 + rl;
      const unsigned short* gp = zg + (size_t)(e0 + r) * 512 + ((c ^ (r & 7)) * 8);
      unsigned short* lp = zs + (s * 16 + wv * 2) * 256;
      GLOAD16(gp, lp);
    }
  }
  LOADW(0, 0); LOADW(1, 1);   // L2 weight prefetch overlaps the DMA drain
  __syncthreads();
  LOADZ(0, 0); LOADZ(1, 1);

  // ---- pass 0: v = Z @ Wv^T -> bf16 ws ----
  GEMM_PASS(0)
#pragma unroll
  for (int a = 0; a < 4; a++) {
    int ch = wn * 64 + a * 16 + rq * 4;
#pragma unroll
    for (int b = 0; b < 4; b++) {
      int edge = wm * 64 + b * 16 + cl;
      u16x4 o;
      o.x = f2bf(acc[a][b][0]); o.y = f2bf(acc[a][b][1]);
      o.z = f2bf(acc[a][b][2]); o.w = f2bf(acc[a][b][3]);
      *(u16x4*)(vws + (size_t)(e0 + edge) * DIM + ch) = o;
    }
  }

  // ---- pass 1: edge_out = Z @ We^T + be (overwrites the Z halves) ----
  GEMM_PASS(1)
#pragma unroll
  for (int a = 0; a < 4; a++) {
    int ch = wn * 64 + a * 16 + rq * 4;
    f32x4 bias = *(const f32x4*)(be + ch);
#pragma unroll
    for (int b = 0; b < 4; b++) {
      int edge = wm * 64 + b * 16 + cl;
      f32x4 o = acc[a][b] + bias;
      *(f32x4*)(edge_out + (size_t)(e0 + edge) * DIM + ch) = o;
    }
  }

  // ---- pass 2: k = Z @ Wk^T, scores in-register, written CSR-permuted ----
  GEMM_PASS(2)
#pragma unroll
  for (int b = 0; b < 4; b++) {
    int edge = wm * 64 + b * 16 + cl;
    int sr = ei[e0 + edge];
    int pe = pos[e0 + edge];
    const float* qp = q + (size_t)sr * DIM + wn * 64 + rq * 4;
    f32x4 q0 = *(const f32x4*)(qp);
    f32x4 q1 = *(const f32x4*)(qp + 16);
    f32x4 q2 = *(const f32x4*)(qp + 32);
    f32x4 q3 = *(const f32x4*)(qp + 48);
    float s0 = acc[0][b][0] * q0[0] + acc[0][b][1] * q0[1] +
               acc[0][b][2] * q0[2] + acc[0][b][3] * q0[3] +
               acc[1][b][0] * q1[0] + acc[1][b][1] * q1[1] +
               acc[1][b][2] * q1[2] + acc[1][b][3] * q1[3];
    float s1 = acc[2][b][0] * q2[0] + acc[2][b][1] * q2[1] +
               acc[2][b][2] * q2[2] + acc[2][b][3] * q2[3] +
               acc[3][b][0] * q3[0] + acc[3][b][1] * q3[1] +
               acc[3][b][2] * q3[2] + acc[3][b][3] * q3[3];
    s0 += __shfl_xor(s0, 16); s0 += __shfl_xor(s0, 32);
    s1 += __shfl_xor(s1, 16); s1 += __shfl_xor(s1, 32);
    if (lane < 16) {
      sperm[(size_t)pe * 8 + wn * 2 + 0] = s0 * 0.17677669529663687f;
      sperm[(size_t)pe * 8 + wn * 2 + 1] = s1 * 0.17677669529663687f;
    }
  }
#undef LOADW
#undef LOADZ
#undef GEMM_PASS
}

// ---------- CSR build ----------
__global__ __launch_bounds__(256) void count_kernel(const int* __restrict__ ei,
                                                    int* __restrict__ counts) {
  int e = blockIdx.x * 256 + threadIdx.x;
  if (e < NE) atomicAdd(&counts[ei[e]], 1);
}

__global__ __launch_bounds__(256) void scan_kernel(const int* __restrict__ counts,
                                                   int* __restrict__ offs,
                                                   int* __restrict__ cursor) {
  __shared__ int tmp[256];
  __shared__ int carry;
  int tid = threadIdx.x;
  if (tid == 0) carry = 0;
  __syncthreads();
  for (int base = 0; base < NN; base += 256) {
    int i = base + tid;
    int v = (i < NN) ? counts[i] : 0;
    tmp[tid] = v;
    __syncthreads();
    for (int off = 1; off < 256; off <<= 1) {
      int t = (tid >= off) ? tmp[tid - off] : 0;
      __syncthreads();
      tmp[tid] += t;
      __syncthreads();
    }
    int incl = tmp[tid];
    int c0 = carry;
    if (i < NN) {
      offs[i] = c0 + incl - v;
      cursor[i] = c0 + incl - v;
    }
    __syncthreads();
    if (tid == 255) carry = c0 + incl;
    __syncthreads();
  }
  if (tid == 0) offs[NN] = carry;
}

__global__ __launch_bounds__(256) void fill_kernel(const int* __restrict__ ei,
                                                   int* __restrict__ cursor,
                                                   int* __restrict__ eids,
                                                   int* __restrict__ pos) {
  int e = blockIdx.x * 256 + threadIdx.x;
  if (e < NE) {
    int p = atomicAdd(&cursor[ei[e]], 1);
    eids[p] = e;
    pos[e] = p;
  }
}

// One wave per src node: online softmax; scores sequential (permuted), v gathered
// with a 2-stage pipeline.
__global__ __launch_bounds__(256) void node_kernel(const int* __restrict__ offs,
                                                   const int* __restrict__ eids,
                                                   const float* __restrict__ sperm,
                                                   const unsigned short* __restrict__ vws,
                                                   float* __restrict__ out) {
  int tid = threadIdx.x;
  int n = blockIdx.x * 4 + (tid >> 6);
  int lane = tid & 63, h = lane >> 3;
  int o0 = offs[n], deg = offs[n + 1] - o0;
  float m = -INFINITY, s = 0.f;
  float a0 = 0.f, a1 = 0.f, a2 = 0.f, a3 = 0.f;
  int e = (deg > 0) ? eids[o0] : 0;
  u16x4 v = *(const u16x4*)(vws + (size_t)e * DIM + lane * 4);
  for (int i = 0; i < deg; i++) {
    int en = (i + 1 < deg) ? eids[o0 + i + 1] : e;
    u16x4 vn = *(const u16x4*)(vws + (size_t)en * DIM + lane * 4);
    float sc = sperm[(size_t)(o0 + i) * 8 + h];
    float mn = fmaxf(m, sc);
    float scale = __expf(m - mn);
    float p = __expf(sc - mn);
    s = s * scale + p;
    m = mn;
    a0 = a0 * scale + p * bf2f(v.x);
    a1 = a1 * scale + p * bf2f(v.y);
    a2 = a2 * scale + p * bf2f(v.z);
    a3 = a3 * scale + p * bf2f(v.w);
    v = vn;
  }
  float inv = 1.f / (s + 1e-16f);
  f32x4 o;
  o.x = a0 * inv; o.y = a1 * inv; o.z = a2 * inv; o.w = a3 * inv;
  *(f32x4*)(out + (size_t)n * DIM + lane * 4) = o;
}

extern "C" void kernel_launch(void* const* d_in, const int* in_sizes, int n_in,
                              void* d_out, int out_size, void* d_ws, size_t ws_size,
                              hipStream_t stream) {
  const float* x = (const float*)d_in[0];
  const int* ei = (const int*)d_in[1];
  const float* ea = (const float*)d_in[2];
  const float* Wq = (const float*)d_in[3];
  const float* Wk = (const float*)d_in[4];
  const float* Wv = (const float*)d_in[5];
  const float* We = (const float*)d_in[6];
  const float* be = (const float*)d_in[7];

  float* out = (float*)d_out;                       // [NN, 256]
  float* edge_out = out + (size_t)NN * DIM;         // [NE, 256] f32
  unsigned short* zg = (unsigned short*)edge_out;   // Z bf16 in rows' first half (stride 512 u16)
  float* q = out;                                   // q scratch (overwritten by node_kernel)

  char* ws = (char*)d_ws;
  unsigned short* wfq = (unsigned short*)(ws + 0);
  unsigned short* wfk = (unsigned short*)(ws + 131072);
  unsigned short* wfv = (unsigned short*)(ws + 262144);
  unsigned short* wfe = (unsigned short*)(ws + 393216);
  unsigned short* vws = (unsigned short*)(ws + 524288);            // [NE,256] bf16
  float* sperm = (float*)(ws + 524288 + 163840000);                // [NE,8] f32, CSR order
  int* counts = (int*)(ws + 524288 + 163840000 + 10240000);
  int* offs   = (int*)(ws + 524288 + 163840000 + 10240000 + 80000);
  int* cursor = (int*)(ws + 524288 + 163840000 + 10240000 + 160016);
  int* eids   = (int*)(ws + 524288 + 163840000 + 10240000 + 240016);
  int* pos    = (int*)(ws + 524288 + 163840000 + 10240000 + 240016 + 1280000);

  hipMemsetAsync(counts, 0, NN * sizeof(int), stream);

  pack_w<<<32, 256, 0, stream>>>(Wq, wfq);
  pack_w<<<32, 256, 0, stream>>>(Wk, wfk);
  pack_w<<<32, 256, 0, stream>>>(Wv, wfv);
  pack_w<<<32, 256, 0, stream>>>(We, wfe);

  zprep<<<NE / 16, 256, 0, stream>>>(x, ei, ea, zg);

  count_kernel<<<(NE + 255) / 256, 256, 0, stream>>>(ei, counts);
  scan_kernel<<<1, 256, 0, stream>>>(counts, offs, cursor);
  fill_kernel<<<(NE + 255) / 256, 256, 0, stream>>>(ei, cursor, eids, pos);

  q_kernel<<<(NN + 63) / 64, 256, 0, stream>>>(x, wfq, q);

  gemm_edge<<<NE / 128, 512, 0, stream>>>(zg, ei, pos, wfk, wfv, wfe, be, q,
                                          vws, sperm, edge_out);

  node_kernel<<<NN / 4, 256, 0, stream>>>(offs, eids, sperm, vws, out);
}

// Round 6
// 617.295 us; speedup vs baseline: 2.8348x; 1.0041x over previous
//
#include <hip/hip_runtime.h>
#include <math.h>

#define NN 20000
#define NE 320000
#define DIM 256

typedef __bf16 bf16x8 __attribute__((ext_vector_type(8)));
typedef float f32x4 __attribute__((ext_vector_type(4)));
typedef int i32x4 __attribute__((ext_vector_type(4)));
typedef unsigned short u16x4 __attribute__((ext_vector_type(4)));

union B8 { i32x4 i; bf16x8 b; };

__device__ __forceinline__ unsigned short f2bf(float f) {
  unsigned int u; __builtin_memcpy(&u, &f, 4);
  u += 0x7fffu + ((u >> 16) & 1u);
  return (unsigned short)(u >> 16);
}
__device__ __forceinline__ float bf2f(unsigned short h) {
  unsigned int u = ((unsigned int)h) << 16;
  float f; __builtin_memcpy(&f, &u, 4);
  return f;
}

#define GLOAD16(gp, lp)                                                        \
  __builtin_amdgcn_global_load_lds(                                            \
      (const __attribute__((address_space(1))) unsigned int*)(gp),             \
      (__attribute__((address_space(3))) unsigned int*)(lp), 16, 0, 0)

// Pack one f32 [256][256] weight (row-major W[j_out][k]) into MFMA fragment order, bf16.
__global__ __launch_bounds__(256) void pack_w(const float* __restrict__ W,
                                              unsigned short* __restrict__ wf) {
  int t = blockIdx.x * 256 + threadIdx.x;    // 0..8191
  int lane = t & 63, ct = (t >> 6) & 15, ks = t >> 10;
  int col = ct * 16 + (lane & 15);
  int k0 = ks * 32 + (lane >> 4) * 8;
  const float* src = W + col * 256 + k0;
  unsigned int h[8];
#pragma unroll
  for (int j = 0; j < 8; j++) h[j] = f2bf(src[j]);
  i32x4 v;
  v.x = (int)(h[0] | (h[1] << 16));
  v.y = (int)(h[2] | (h[3] << 16));
  v.z = (int)(h[4] | (h[5] << 16));
  v.w = (int)(h[6] | (h[7] << 16));
  ((i32x4*)wf)[t] = v;
}

// Z = bf16(ea * x[dst]) written in MFMA FRAGMENT ORDER, 64KB per 128-edge tile,
// placed at tile*128KB (aliased over edge_out rows of the SAME gemm block).
// idx bits: lane 0-5, bt 6-8, ks 9-11, tile 12+.  Needs NE*32 threads total.
__global__ __launch_bounds__(256) void zprep(const float* __restrict__ x,
                                             const int* __restrict__ ei,
                                             const float* __restrict__ ea,
                                             unsigned short* __restrict__ zg) {
  int idx = blockIdx.x * 256 + threadIdx.x;   // NE*32 threads
  int lane = idx & 63;
  int bt = (idx >> 6) & 7;
  int ks = (idx >> 9) & 7;
  int tile = idx >> 12;
  int e = tile * 128 + bt * 16 + (lane & 15);
  int kf = ks * 32 + (lane >> 4) * 8;
  int dst = ei[NE + e];
  const f32x4* ap = (const f32x4*)(ea + (size_t)e * DIM + kf);
  const f32x4* xp = (const f32x4*)(x + (size_t)dst * DIM + kf);
  f32x4 p0 = ap[0] * xp[0];
  f32x4 p1 = ap[1] * xp[1];
  unsigned int h[8];
  h[0] = f2bf(p0.x); h[1] = f2bf(p0.y); h[2] = f2bf(p0.z); h[3] = f2bf(p0.w);
  h[4] = f2bf(p1.x); h[5] = f2bf(p1.y); h[6] = f2bf(p1.z); h[7] = f2bf(p1.w);
  i32x4 o;
  o.x = (int)(h[0] | (h[1] << 16));
  o.y = (int)(h[2] | (h[3] << 16));
  o.z = (int)(h[4] | (h[5] << 16));
  o.w = (int)(h[6] | (h[7] << 16));
  size_t byteo = (size_t)tile * 131072 + (size_t)(idx & 4095) * 16;
  *(i32x4*)((char*)zg + byteo) = o;
}

// ---------- q kernel (64-row tiles) ----------
__device__ __forceinline__ void gemm_tile(const unsigned short* zs,
                                          const unsigned short* wf,
                                          int lane, int wv, f32x4 (&acc)[4][4]) {
#pragma unroll 1
  for (int ksI = 0; ksI < 8; ksI++) {
    bf16x8 afr[4], bfr[4];
#pragma unroll
    for (int rt = 0; rt < 4; rt++) {
      int row = rt * 16 + (lane & 15);
      int k = ksI * 32 + (lane >> 4) * 8;
      int byteo = (row * 512 + k * 2) ^ ((row & 7) << 4);
      B8 u; u.i = *(const i32x4*)((const char*)zs + byteo);
      afr[rt] = u.b;
    }
#pragma unroll
    for (int ct = 0; ct < 4; ct++) {
      B8 u; u.i = ((const i32x4*)wf)[ksI * 1024 + (wv * 4 + ct) * 64 + lane];
      bfr[ct] = u.b;
    }
#pragma unroll
    for (int rt = 0; rt < 4; rt++)
#pragma unroll
      for (int ct = 0; ct < 4; ct++)
        acc[rt][ct] = __builtin_amdgcn_mfma_f32_16x16x32_bf16(afr[rt], bfr[ct], acc[rt][ct], 0, 0, 0);
  }
}

__global__ __launch_bounds__(256) void q_kernel(const float* __restrict__ x,
                                                const unsigned short* __restrict__ wf,
                                                float* __restrict__ q) {
  __shared__ unsigned short zs[64 * 256];
  int tid = threadIdx.x, lane = tid & 63, wv = tid >> 6;
  int r0 = blockIdx.x * 64;
  int dcol = lane * 4;
#pragma unroll 4
  for (int rr = 0; rr < 16; rr++) {
    int r = rr * 4 + wv;
    int row = r0 + r;
    f32x4 a = {0.f, 0.f, 0.f, 0.f};
    if (row < NN) a = *(const f32x4*)(x + (size_t)row * DIM + dcol);
    u16x4 z;
    z.x = f2bf(a.x); z.y = f2bf(a.y); z.z = f2bf(a.z); z.w = f2bf(a.w);
    int byteo = (r * 512 + dcol * 2) ^ ((r & 7) << 4);
    *(u16x4*)((char*)zs + byteo) = z;
  }
  __syncthreads();
  f32x4 acc[4][4];
#pragma unroll
  for (int rt = 0; rt < 4; rt++)
#pragma unroll
    for (int ct = 0; ct < 4; ct++) acc[rt][ct] = (f32x4){0.f, 0.f, 0.f, 0.f};
  gemm_tile(zs, wf, lane, wv, acc);
  int cq = lane & 15, rq = lane >> 4;
#pragma unroll
  for (int ct = 0; ct < 4; ct++) {
    int col = wv * 64 + ct * 16 + cq;
#pragma unroll
    for (int rt = 0; rt < 4; rt++) {
#pragma unroll
      for (int j = 0; j < 4; j++) {
        int row = r0 + rt * 16 + rq * 4 + j;
        if (row < NN) q[(size_t)row * DIM + col] = acc[rt][ct][j];
      }
    }
  }
}

// ---------- edge GEMM: fragment-order async-staged Z tile, 3 passes ----------
__global__ __launch_bounds__(512) void gemm_edge(
    const unsigned short* __restrict__ zg, const int* __restrict__ ei,
    const int* __restrict__ pos,
    const unsigned short* __restrict__ wfk, const unsigned short* __restrict__ wfv,
    const unsigned short* __restrict__ wfe, const float* __restrict__ be,
    const float* __restrict__ q, unsigned short* __restrict__ vws,
    float* __restrict__ sperm, float* __restrict__ edge_out) {
  __shared__ unsigned short zs[128 * 256];   // 64 KiB, fragment order (linear)
  int tid = threadIdx.x, lane = tid & 63, wv = tid >> 6;
  int wm = wv >> 2, wn = wv & 3;
  int rq = lane >> 4, cl = lane & 15;
  int e0 = blockIdx.x * 128;

  const unsigned short* wfs[3] = {wfv, wfe, wfk};
  i32x4 wbuf[4][4];   // 4-slot ring, lead-3 weight prefetch (L2)
  i32x4 zbuf[2][4];   // 2-slot ring, lead-1 Z-fragment prefetch (LDS)
  f32x4 acc[4][4];

#define LOADW(S, SLOT)                                                         \
  {                                                                            \
    const unsigned short* wfp = wfs[(S) >> 3];                                 \
    _Pragma("unroll") for (int a = 0; a < 4; a++)                              \
        wbuf[SLOT][a] =                                                        \
            ((const i32x4*)wfp)[((S) & 7) * 1024 + (wn * 4 + a) * 64 + lane];  \
  }
#define LOADZ(S, SLOT)                                                         \
  {                                                                            \
    _Pragma("unroll") for (int b = 0; b < 4; b++) {                            \
      int fi = ((S) & 7) * 8 + wm * 4 + b;                                     \
      zbuf[SLOT][b] = *(const i32x4*)(zs + fi * 512 + lane * 8);               \
    }                                                                          \
  }
#define GEMM_PASS(P)                                                           \
  _Pragma("unroll") for (int a = 0; a < 4; a++)                                \
      _Pragma("unroll") for (int b = 0; b < 4; b++)                            \
          acc[a][b] = (f32x4){0.f, 0.f, 0.f, 0.f};                             \
  _Pragma("unroll") for (int ks = 0; ks < 8; ks++) {                           \
    const int step = (P) * 8 + ks;                                             \
    if (step + 3 < 24) LOADW(step + 3, (step + 3) & 3);                        \
    if (step + 1 < 24) LOADZ(step + 1, (step + 1) & 1);                        \
    _Pragma("unroll") for (int a = 0; a < 4; a++) {                            \
      B8 w; w.i = wbuf[step & 3][a];                                           \
      _Pragma("unroll") for (int b = 0; b < 4; b++) {                          \
        B8 z; z.i = zbuf[step & 1][b];                                         \
        acc[a][b] = __builtin_amdgcn_mfma_f32_16x16x32_bf16(w.b, z.b,          \
                                                            acc[a][b], 0, 0, 0); \
      }                                                                        \
    }                                                                          \
  }

  // async stage: linear fragment-order copy. One GLOAD16 = 64 lanes x 16B = 1KB.
  // 64 slabs of 1KB; wave wv stages slabs wv*8 .. wv*8+7.
  {
    const char* gbase = (const char*)zg + (size_t)blockIdx.x * 131072;
#pragma unroll
    for (int s = 0; s < 8; s++) {
      int slab = wv * 8 + s;
      const char* gp = gbase + slab * 1024 + lane * 16;
      unsigned short* lp = zs + slab * 512;   // u16 units: 1024B per slab
      GLOAD16(gp, lp);
    }
  }
  LOADW(0, 0); LOADW(1, 1); LOADW(2, 2);  // L2 weight prefetch overlaps DMA drain
  __syncthreads();
  LOADZ(0, 0); LOADZ(1, 1);

  // ---- pass 0: v = Z @ Wv^T -> bf16 ws ----
  GEMM_PASS(0)
#pragma unroll
  for (int a = 0; a < 4; a++) {
    int ch = wn * 64 + a * 16 + rq * 4;
#pragma unroll
    for (int b = 0; b < 4; b++) {
      int edge = wm * 64 + b * 16 + cl;
      u16x4 o;
      o.x = f2bf(acc[a][b][0]); o.y = f2bf(acc[a][b][1]);
      o.z = f2bf(acc[a][b][2]); o.w = f2bf(acc[a][b][3]);
      *(u16x4*)(vws + (size_t)(e0 + edge) * DIM + ch) = o;
    }
  }

  // ---- pass 1: edge_out = Z @ We^T + be (overwrites this block's zg region) ----
  GEMM_PASS(1)
#pragma unroll
  for (int a = 0; a < 4; a++) {
    int ch = wn * 64 + a * 16 + rq * 4;
    f32x4 bias = *(const f32x4*)(be + ch);
#pragma unroll
    for (int b = 0; b < 4; b++) {
      int edge = wm * 64 + b * 16 + cl;
      f32x4 o = acc[a][b] + bias;
      *(f32x4*)(edge_out + (size_t)(e0 + edge) * DIM + ch) = o;
    }
  }

  // ---- pass 2: k = Z @ Wk^T, scores in-register, written CSR-permuted ----
  GEMM_PASS(2)
#pragma unroll
  for (int b = 0; b < 4; b++) {
    int edge = wm * 64 + b * 16 + cl;
    int sr = ei[e0 + edge];
    int pe = pos[e0 + edge];
    const float* qp = q + (size_t)sr * DIM + wn * 64 + rq * 4;
    f32x4 q0 = *(const f32x4*)(qp);
    f32x4 q1 = *(const f32x4*)(qp + 16);
    f32x4 q2 = *(const f32x4*)(qp + 32);
    f32x4 q3 = *(const f32x4*)(qp + 48);
    float s0 = acc[0][b][0] * q0[0] + acc[0][b][1] * q0[1] +
               acc[0][b][2] * q0[2] + acc[0][b][3] * q0[3] +
               acc[1][b][0] * q1[0] + acc[1][b][1] * q1[1] +
               acc[1][b][2] * q1[2] + acc[1][b][3] * q1[3];
    float s1 = acc[2][b][0] * q2[0] + acc[2][b][1] * q2[1] +
               acc[2][b][2] * q2[2] + acc[2][b][3] * q2[3] +
               acc[3][b][0] * q3[0] + acc[3][b][1] * q3[1] +
               acc[3][b][2] * q3[2] + acc[3][b][3] * q3[3];
    s0 += __shfl_xor(s0, 16); s0 += __shfl_xor(s0, 32);
    s1 += __shfl_xor(s1, 16); s1 += __shfl_xor(s1, 32);
    if (lane < 16) {
      sperm[(size_t)pe * 8 + wn * 2 + 0] = s0 * 0.17677669529663687f;
      sperm[(size_t)pe * 8 + wn * 2 + 1] = s1 * 0.17677669529663687f;
    }
  }
#undef LOADW
#undef LOADZ
#undef GEMM_PASS
}

// ---------- CSR build ----------
__global__ __launch_bounds__(256) void count_kernel(const int* __restrict__ ei,
                                                    int* __restrict__ counts) {
  int e = blockIdx.x * 256 + threadIdx.x;
  if (e < NE) atomicAdd(&counts[ei[e]], 1);
}

// One block, per-thread 79-element chunk + shfl wave scan.
__global__ __launch_bounds__(256) void scan_kernel(const int* __restrict__ counts,
                                                   int* __restrict__ offs,
                                                   int* __restrict__ cursor) {
  const int CH = 79;                      // 256*79 = 20224 >= NN
  int tid = threadIdx.x;
  int lane = tid & 63, wv = tid >> 6;
  int b0 = tid * CH;
  int sum = 0;
  for (int j = 0; j < CH; j++) {
    int i = b0 + j;
    if (i < NN) sum += counts[i];
  }
  int pre = sum;
  for (int d = 1; d < 64; d <<= 1) {
    int t = __shfl_up(pre, d);
    if (lane >= d) pre += t;
  }
  __shared__ int wsum[4];
  if (lane == 63) wsum[wv] = pre;
  __syncthreads();
  int base = 0;
  for (int w = 0; w < wv; w++) base += wsum[w];
  int running = base + pre - sum;         // exclusive prefix at b0
  for (int j = 0; j < CH; j++) {
    int i = b0 + j;
    if (i < NN) {
      offs[i] = running;
      cursor[i] = running;
      running += counts[i];
    }
  }
  if (tid == 255) offs[NN] = running;
}

__global__ __launch_bounds__(256) void fill_kernel(const int* __restrict__ ei,
                                                   int* __restrict__ cursor,
                                                   int* __restrict__ eids,
                                                   int* __restrict__ pos) {
  int e = blockIdx.x * 256 + threadIdx.x;
  if (e < NE) {
    int p = atomicAdd(&cursor[ei[e]], 1);
    eids[p] = e;
    pos[e] = p;
  }
}

// One wave per src node: online softmax; scores sequential (permuted), v gathered
// with a 2-stage pipeline.
__global__ __launch_bounds__(256) void node_kernel(const int* __restrict__ offs,
                                                   const int* __restrict__ eids,
                                                   const float* __restrict__ sperm,
                                                   const unsigned short* __restrict__ vws,
                                                   float* __restrict__ out) {
  int tid = threadIdx.x;
  int n = blockIdx.x * 4 + (tid >> 6);
  int lane = tid & 63, h = lane >> 3;
  int o0 = offs[n], deg = offs[n + 1] - o0;
  float m = -INFINITY, s = 0.f;
  float a0 = 0.f, a1 = 0.f, a2 = 0.f, a3 = 0.f;
  int e = (deg > 0) ? eids[o0] : 0;
  u16x4 v = *(const u16x4*)(vws + (size_t)e * DIM + lane * 4);
  for (int i = 0; i < deg; i++) {
    int en = (i + 1 < deg) ? eids[o0 + i + 1] : e;
    u16x4 vn = *(const u16x4*)(vws + (size_t)en * DIM + lane * 4);
    float sc = sperm[(size_t)(o0 + i) * 8 + h];
    float mn = fmaxf(m, sc);
    float scale = __expf(m - mn);
    float p = __expf(sc - mn);
    s = s * scale + p;
    m = mn;
    a0 = a0 * scale + p * bf2f(v.x);
    a1 = a1 * scale + p * bf2f(v.y);
    a2 = a2 * scale + p * bf2f(v.z);
    a3 = a3 * scale + p * bf2f(v.w);
    v = vn;
  }
  float inv = 1.f / (s + 1e-16f);
  f32x4 o;
  o.x = a0 * inv; o.y = a1 * inv; o.z = a2 * inv; o.w = a3 * inv;
  *(f32x4*)(out + (size_t)n * DIM + lane * 4) = o;
}

extern "C" void kernel_launch(void* const* d_in, const int* in_sizes, int n_in,
                              void* d_out, int out_size, void* d_ws, size_t ws_size,
                              hipStream_t stream) {
  const float* x = (const float*)d_in[0];
  const int* ei = (const int*)d_in[1];
  const float* ea = (const float*)d_in[2];
  const float* Wq = (const float*)d_in[3];
  const float* Wk = (const float*)d_in[4];
  const float* Wv = (const float*)d_in[5];
  const float* We = (const float*)d_in[6];
  const float* be = (const float*)d_in[7];

  float* out = (float*)d_out;                       // [NN, 256]
  float* edge_out = out + (size_t)NN * DIM;         // [NE, 256] f32
  unsigned short* zg = (unsigned short*)edge_out;   // Z packed: tile t -> 64KB at t*128KB
  float* q = out;                                   // q scratch (overwritten by node_kernel)

  char* ws = (char*)d_ws;
  unsigned short* wfq = (unsigned short*)(ws + 0);
  unsigned short* wfk = (unsigned short*)(ws + 131072);
  unsigned short* wfv = (unsigned short*)(ws + 262144);
  unsigned short* wfe = (unsigned short*)(ws + 393216);
  unsigned short* vws = (unsigned short*)(ws + 524288);            // [NE,256] bf16
  float* sperm = (float*)(ws + 524288 + 163840000);                // [NE,8] f32, CSR order
  int* counts = (int*)(ws + 524288 + 163840000 + 10240000);
  int* offs   = (int*)(ws + 524288 + 163840000 + 10240000 + 80000);
  int* cursor = (int*)(ws + 524288 + 163840000 + 10240000 + 160016);
  int* eids   = (int*)(ws + 524288 + 163840000 + 10240000 + 240016);
  int* pos    = (int*)(ws + 524288 + 163840000 + 10240000 + 240016 + 1280000);

  hipMemsetAsync(counts, 0, NN * sizeof(int), stream);

  pack_w<<<32, 256, 0, stream>>>(Wq, wfq);
  pack_w<<<32, 256, 0, stream>>>(Wk, wfk);
  pack_w<<<32, 256, 0, stream>>>(Wv, wfv);
  pack_w<<<32, 256, 0, stream>>>(We, wfe);

  zprep<<<NE * 32 / 256, 256, 0, stream>>>(x, ei, ea, zg);

  count_kernel<<<(NE + 255) / 256, 256, 0, stream>>>(ei, counts);
  scan_kernel<<<1, 256, 0, stream>>>(counts, offs, cursor);
  fill_kernel<<<(NE + 255) / 256, 256, 0, stream>>>(ei, cursor, eids, pos);

  q_kernel<<<(NN + 63) / 64, 256, 0, stream>>>(x, wfq, q);

  gemm_edge<<<NE / 128, 512, 0, stream>>>(zg, ei, pos, wfk, wfv, wfe, be, q,
                                          vws, sperm, edge_out);

  node_kernel<<<NN / 4, 256, 0, stream>>>(offs, eids, sperm, vws, out);
}